// Round 4
// baseline (3672.864 us; speedup 1.0000x reference)
//
#include <hip/hip_runtime.h>
#include <cstdint>
#include <cstddef>

// PCFG inside algorithm. B=8, n=28, NT=32, T=64, ST=96.
// Single block (1024 threads) per batch; ALL DP state in LDS; zero global
// round-trips between widths; no inter-block sync at all.
//
// State: eBeta[w][a][s] = exp(beta[w][s][a] - bmax[w][s]) (triangular rows
// w=1..n-1), bmax triangle, bmax0/el0T for terminal row. Per width w:
//   Mspan[s] = max_k bmax[k][s] + bmax[w-1-k][s+k+1]
//   right-scaled tables: erNsc[k][r][s] = eBeta[w-1-k][r][s+k+1] * g(k,s)
//                        erTsc[t][s]    = el0T[t][s+w] * gT(s)
//   numer chunks (256 pair-columns) built into LDS, contracted against the
//   packed E tables (float4 per (c-quad, a)) streamed from L2.
// Quadrant c-space: w==1: TT (4096) ; w>=2: TN(2048) | NT(2048) | NN(1024 @ w>=3).

#define NMAX 28

__device__ __forceinline__ int off32(int w, int n) {
    return (w - 1) * n - (w * (w - 1)) / 2;   // row start (span units) of width-w row
}

// ---- mrule[b][a] = max over 96x96 of rule_scores[b][a] ----
__global__ __launch_bounds__(256) void mrule_kernel(const float* __restrict__ rule,
                                                    float* __restrict__ mrule) {
    int a = blockIdx.x, b = blockIdx.y, tid = threadIdx.x;
    const float* base = rule + (size_t)(b * 32 + a) * 9216;
    float v = -3.0e38f;
    for (int i = tid; i < 9216; i += 256) v = fmaxf(v, base[i]);
    for (int off = 32; off > 0; off >>= 1) v = fmaxf(v, __shfl_xor(v, off, 64));
    __shared__ float red[4];
    if ((tid & 63) == 0) red[tid >> 6] = v;
    __syncthreads();
    if (tid == 0)
        mrule[b * 32 + a] = fmaxf(fmaxf(red[0], red[1]), fmaxf(red[2], red[3]));
}

// ---- pack erule = exp(rule - mrule) into quadrant arrays, [c4][a][4] ----
__global__ __launch_bounds__(256) void pack_kernel(const float* __restrict__ rule,
                                                   const float* __restrict__ mrule,
                                                   float* __restrict__ E_TT,
                                                   float* __restrict__ E_TN,
                                                   float* __restrict__ E_NT,
                                                   float* __restrict__ E_NN) {
    int b = blockIdx.y, tid = threadIdx.x;
    int a = tid & 31;
    int cc = blockIdx.x * 8 + (tid >> 5); // 0..2303
    float mr = mrule[b * 32 + a];
    int l, r;
    float* dst;
    if (cc < 1024) {
        int flat = cc * 4;
        l = 32 + (flat >> 6); r = 32 + (flat & 63);
        dst = E_TT + ((size_t)(b * 1024 + cc) * 32 + a) * 4;
    } else if (cc < 1536) {
        int flat = (cc - 1024) * 4;
        l = 32 + (flat >> 5); r = flat & 31;
        dst = E_TN + ((size_t)(b * 512 + (cc - 1024)) * 32 + a) * 4;
    } else if (cc < 2048) {
        int flat = (cc - 1536) * 4;
        l = flat >> 6; r = 32 + (flat & 63);
        dst = E_NT + ((size_t)(b * 512 + (cc - 1536)) * 32 + a) * 4;
    } else {
        int flat = (cc - 2048) * 4;
        l = flat >> 5; r = flat & 31;
        dst = E_NN + ((size_t)(b * 256 + (cc - 2048)) * 32 + a) * 4;
    }
    const float4 v = *(const float4*)(rule + (((size_t)(b * 32 + a) * 96 + l) * 96 + r));
    float4 o;
    o.x = expf(v.x - mr); o.y = expf(v.y - mr);
    o.z = expf(v.z - mr); o.w = expf(v.w - mr);
    *(float4*)dst = o;
}

// LDS float offsets
#define O_EBETA 0            // 12096: rows w=1..27, row: [a(32)][s(n-w)]
#define O_EL0T  12096        // 1792:  [t(64)][NMAX]
#define O_ERNSC 13888        // 5824:  [k][r(32)][s(S)]  (k=0..w-2)
#define O_ERTSC 19712        // 1728:  [t(64)][s(S)]
#define O_BMAX0 21440        // 28
#define O_BMAXN 21472        // 378 (triangle, same off32/row layout in span units)
#define O_MSPAN 21856        // 32
#define O_EMRUL 21888        // 32
#define O_NUMER 21920        // 2 * 256*34 = 17408 (double-buffered chunk, pitch 34)
#define O_RED   O_ERNSC      // alias (2048 <= 5824), live only between barriers
#define LDS_FLOATS (O_NUMER + 17408)

__global__ __launch_bounds__(1024, 1) void inside_kernel(
    const float* __restrict__ unary, const float* __restrict__ mrule,
    const float* __restrict__ root,
    const float* __restrict__ E_TT, const float* __restrict__ E_TN,
    const float* __restrict__ E_NT, const float* __restrict__ E_NN,
    float* __restrict__ out, int n) {
    extern __shared__ float lds[];
    const int b = blockIdx.x, tid = threadIdx.x;
    const int a = tid & 31;
    const int sp = (tid >> 5) & 15;   // span-pair slot (spans 2sp, 2sp+1)
    const int chf = tid >> 9;         // c-half 0..1

    // ---- prologue: emrule, bmax0, el0T ----
    if (tid < 32) lds[O_EMRUL + tid] = expf(mrule[b * 32 + tid]);
    for (int p = 0; p < 2; ++p) {
        int s = p * 16 + (tid >> 6), t = tid & 63;
        if (s < n) {
            float v = unary[((size_t)(b * n + s)) * 64 + t];
            float m = v;
            for (int off = 32; off > 0; off >>= 1) m = fmaxf(m, __shfl_xor(m, off, 64));
            if (t == 0) lds[O_BMAX0 + s] = m;
            lds[O_EL0T + t * NMAX + s] = expf(v - m);
        }
    }
    __syncthreads();

    for (int w = 1; w < n; ++w) {
        const int S = n - w;
        const int nc = (w >= 3) ? 20 : 16;

        // ---- A: Mspan ----
        if (tid < S) {
            int s = tid;
            float M = -3.0e38f;
            for (int k = 0; k < w; ++k) {
                float bl = (k == 0) ? lds[O_BMAX0 + s] : lds[O_BMAXN + off32(k, n) + s];
                int wr = w - 1 - k;
                float br = (wr == 0) ? lds[O_BMAX0 + s + k + 1]
                                     : lds[O_BMAXN + off32(wr, n) + s + k + 1];
                M = fmaxf(M, bl + br);
            }
            lds[O_MSPAN + s] = M;
        }
        __syncthreads();

        // ---- B: right-scaled tables ----
        {   // erTsc[t][s]
            for (int idx = tid; idx < 64 * 32; idx += 1024) {
                int s = idx & 31, t = idx >> 5;
                if (s < S) {
                    float bw1 = (w == 1) ? lds[O_BMAX0 + s]
                                         : lds[O_BMAXN + off32(w - 1, n) + s];
                    float g = expf(lds[O_BMAX0 + s + w] + bw1 - lds[O_MSPAN + s]);
                    lds[O_ERTSC + t * S + s] = lds[O_EL0T + t * NMAX + (s + w)] * g;
                }
            }
            // erNsc[k][r][s], k = 0..w-2 (right width wr = w-1-k >= 1)
            for (int k = 0; k < w - 1; ++k) {
                int s = tid & 31, r = (tid >> 5) & 31;
                if (tid < 1024 && s < S) {
                    int wr = w - 1 - k;
                    float bl = (k == 0) ? lds[O_BMAX0 + s] : lds[O_BMAXN + off32(k, n) + s];
                    float g = expf(bl + lds[O_BMAXN + off32(wr, n) + s + k + 1]
                                   - lds[O_MSPAN + s]);
                    lds[O_ERNSC + k * (32 * S) + r * S + s] =
                        lds[O_EBETA + off32(wr, n) * 32 + r * (n - wr) + (s + k + 1)] * g;
                }
            }
        }
        __syncthreads();

        // ---- chunk pipeline ----
        const int s_b = tid & 31;      // build span
        const int cL0 = tid >> 5;      // build column base 0..31
        auto BUILD = [&](int c) {
            float* buf = lds + O_NUMER + (c & 1) * 8704;
            int cbase = c * 256;
            if (s_b < S) {
                #pragma unroll
                for (int i = 0; i < 8; ++i) {
                    int cL = cL0 + i * 32;
                    int cc = cbase + cL;
                    float v;
                    if (w == 1) {              // TT
                        int l = cc >> 6, r = cc & 63;
                        v = lds[O_EL0T + l * NMAX + s_b] * lds[O_ERTSC + r * S + s_b];
                    } else if (cc < 2048) {    // TN
                        int l = cc >> 5, r = cc & 31;
                        v = lds[O_EL0T + l * NMAX + s_b] * lds[O_ERNSC + r * S + s_b];
                    } else if (cc < 4096) {    // NT
                        int c2 = cc - 2048; int l = c2 >> 6, r = c2 & 63;
                        v = lds[O_EBETA + off32(w - 1, n) * 32 + l * (n - (w - 1)) + s_b] *
                            lds[O_ERTSC + r * S + s_b];
                    } else {                   // NN
                        int c2 = cc - 4096; int l = c2 >> 5, r = c2 & 31;
                        float acc = 0.f;
                        for (int k = 1; k <= w - 2; ++k)
                            acc = fmaf(lds[O_EBETA + off32(k, n) * 32 + l * (n - k) + s_b],
                                       lds[O_ERNSC + k * (32 * S) + r * S + s_b], acc);
                        v = acc;
                    }
                    buf[cL * 34 + s_b] = v;
                }
            }
        };

        float2 A0 = make_float2(0.f, 0.f), A1 = make_float2(0.f, 0.f);
        auto CONTRACT = [&](int c) {
            const float* buf = lds + O_NUMER + (c & 1) * 8704;
            const float4* Eq; int cqQ;
            if (w == 1)      { Eq = (const float4*)E_TT + (size_t)b * 1024 * 32; cqQ = c * 64; }
            else if (c < 8)  { Eq = (const float4*)E_TN + (size_t)b * 512 * 32;  cqQ = c * 64; }
            else if (c < 16) { Eq = (const float4*)E_NT + (size_t)b * 512 * 32;  cqQ = (c - 8) * 64; }
            else             { Eq = (const float4*)E_NN + (size_t)b * 256 * 32;  cqQ = (c - 16) * 64; }
            const float* nb = buf + 2 * sp;
            const float4* Ebase = Eq + (size_t)(cqQ + chf * 32) * 32 + a;
            #pragma unroll 4
            for (int i = 0; i < 32; ++i) {
                float4 e4 = Ebase[(size_t)i * 32];
                int cL = (chf * 32 + i) * 4;
                float2 n0 = *(const float2*)(nb + (cL + 0) * 34);
                float2 n1 = *(const float2*)(nb + (cL + 1) * 34);
                float2 n2 = *(const float2*)(nb + (cL + 2) * 34);
                float2 n3 = *(const float2*)(nb + (cL + 3) * 34);
                A0.x = fmaf(n0.x, e4.x, A0.x); A0.y = fmaf(n0.y, e4.x, A0.y);
                A1.x = fmaf(n1.x, e4.y, A1.x); A1.y = fmaf(n1.y, e4.y, A1.y);
                A0.x = fmaf(n2.x, e4.z, A0.x); A0.y = fmaf(n2.y, e4.z, A0.y);
                A1.x = fmaf(n3.x, e4.w, A1.x); A1.y = fmaf(n3.y, e4.w, A1.y);
            }
        };

        BUILD(0);
        for (int c = 0; c < nc; ++c) {
            __syncthreads();
            CONTRACT(c);
            if (c + 1 < nc) BUILD(c + 1);
        }
        __syncthreads();

        // ---- reduce + finalize ----
        lds[O_RED + chf * 1024 + (2 * sp) * 32 + a]     = A0.x + A1.x;
        lds[O_RED + chf * 1024 + (2 * sp + 1) * 32 + a] = A0.y + A1.y;
        __syncthreads();
        {
            int s = tid >> 5;
            if (s < S) {
                float sum = lds[O_RED + s * 32 + a] + lds[O_RED + 1024 + s * 32 + a];
                float t2 = sum * lds[O_EMRUL + a];
                float m2 = t2;
                for (int off = 1; off < 32; off <<= 1)
                    m2 = fmaxf(m2, __shfl_xor(m2, off, 64));
                lds[O_EBETA + off32(w, n) * 32 + a * (n - w) + s] = t2 / m2;
                if (a == 0)
                    lds[O_BMAXN + off32(w, n) + s] = logf(m2) + lds[O_MSPAN + s];
            }
        }
        __syncthreads();
    }

    // ---- epilogue: logsumexp over root ----
    if (tid < 32) {
        float eB = lds[O_EBETA + off32(n - 1, n) * 32 + tid];
        float v = eB * expf(root[b * 32 + tid]);
        for (int off = 1; off < 32; off <<= 1) v += __shfl_xor(v, off, 64);
        if (tid == 0) out[b] = lds[O_BMAXN + off32(n - 1, n)] + logf(v);
    }
}

extern "C" void kernel_launch(void* const* d_in, const int* in_sizes, int n_in,
                              void* d_out, int out_size, void* d_ws, size_t ws_size,
                              hipStream_t stream) {
    const float* unary = (const float*)d_in[0]; // B,n,64
    const float* rule  = (const float*)d_in[1]; // B,32,96,96
    const float* root  = (const float*)d_in[2]; // B,32
    float* out = (float*)d_out;

    const int B = in_sizes[2] / 32;
    int n = in_sizes[0] / (B * 64);

    float* ws = (float*)d_ws;
    float* mrule = ws;                          // B*32
    float* E_TT  = mrule + (size_t)B * 32;      // B*1024*32*4
    float* E_TN  = E_TT + (size_t)B * 131072;   // B*512*32*4
    float* E_NT  = E_TN + (size_t)B * 65536;    // B*512*32*4
    float* E_NN  = E_NT + (size_t)B * 65536;    // B*256*32*4

    mrule_kernel<<<dim3(32, B), 256, 0, stream>>>(rule, mrule);
    pack_kernel<<<dim3(288, B), 256, 0, stream>>>(rule, mrule, E_TT, E_TN, E_NT, E_NN);

    static bool attr_set = false;
    hipFuncSetAttribute((const void*)inside_kernel,
                        hipFuncAttributeMaxDynamicSharedMemorySize,
                        LDS_FLOATS * 4);
    (void)attr_set;

    inside_kernel<<<dim3(B), dim3(1024), LDS_FLOATS * 4, stream>>>(
        unary, mrule, root, E_TT, E_TN, E_NT, E_NN, out, n);
}

// Round 5
// 543.611 us; speedup vs baseline: 6.7564x; 6.7564x over previous
//
#include <hip/hip_runtime.h>
#include <cstdint>
#include <cstddef>

// PCFG inside algorithm. B=8, n=28, NT=32, T=64, ST=96.
// Step kernel: grid (CH, B), 512 threads. Block (b,ch) owns 64 float4-columns
// (256 (l,r) pair-columns) of the packed erule table, held in REGISTERS
// (4 float4/thread). All spans of the width processed in parallel.
// Finalization of width w-1 (chunk-partial reduction + log + bmax) is fused
// into step w's prologue, redundantly per block (bitwise identical).
// Partials and Mspan ping-pong between steps. No inter-block sync.
// Quadrants: w==1: TT (16 chunks) ; w>=2: TN(ch 0-7) NT(ch 8-15) NN(ch 16-19, w>=3).

#define PS   27
#define PCH  20
#define NMAX 28

__device__ __forceinline__ float dot4acc(float4 m, float4 t, float acc) {
    return fmaf(m.x, t.x, fmaf(m.y, t.y, fmaf(m.z, t.z, fmaf(m.w, t.w, acc))));
}

// ---- mrule[b][a] = max over 96x96 of rule_scores[b][a] ----
__global__ __launch_bounds__(256) void mrule_kernel(const float* __restrict__ rule,
                                                    float* __restrict__ mrule) {
    int a = blockIdx.x, b = blockIdx.y, tid = threadIdx.x;
    const float* base = rule + (size_t)(b * 32 + a) * 9216;
    float v = -3.0e38f;
    for (int i = tid; i < 9216; i += 256) v = fmaxf(v, base[i]);
    for (int off = 32; off > 0; off >>= 1) v = fmaxf(v, __shfl_xor(v, off, 64));
    __shared__ float red[4];
    if ((tid & 63) == 0) red[tid >> 6] = v;
    __syncthreads();
    if (tid == 0)
        mrule[b * 32 + a] = fmaxf(fmaxf(red[0], red[1]), fmaxf(red[2], red[3]));
}

// ---- pack erule = exp(rule - mrule) into quadrant arrays, [c4][a][4] ----
__global__ __launch_bounds__(256) void pack_kernel(const float* __restrict__ rule,
                                                   const float* __restrict__ mrule,
                                                   float* __restrict__ E_TT,
                                                   float* __restrict__ E_TN,
                                                   float* __restrict__ E_NT,
                                                   float* __restrict__ E_NN) {
    int b = blockIdx.y, tid = threadIdx.x;
    int a = tid & 31;
    int cc = blockIdx.x * 8 + (tid >> 5); // 0..2303
    float mr = mrule[b * 32 + a];
    int l, r;
    float* dst;
    if (cc < 1024) {
        int flat = cc * 4;
        l = 32 + (flat >> 6); r = 32 + (flat & 63);
        dst = E_TT + ((size_t)(b * 1024 + cc) * 32 + a) * 4;
    } else if (cc < 1536) {
        int flat = (cc - 1024) * 4;
        l = 32 + (flat >> 5); r = flat & 31;
        dst = E_TN + ((size_t)(b * 512 + (cc - 1024)) * 32 + a) * 4;
    } else if (cc < 2048) {
        int flat = (cc - 1536) * 4;
        l = flat >> 6; r = 32 + (flat & 63);
        dst = E_NT + ((size_t)(b * 512 + (cc - 1536)) * 32 + a) * 4;
    } else {
        int flat = (cc - 2048) * 4;
        l = flat >> 5; r = flat & 31;
        dst = E_NN + ((size_t)(b * 256 + (cc - 2048)) * 32 + a) * 4;
    }
    const float4 v = *(const float4*)(rule + (((size_t)(b * 32 + a) * 96 + l) * 96 + r));
    float4 o;
    o.x = expf(v.x - mr); o.y = expf(v.y - mr);
    o.z = expf(v.z - mr); o.w = expf(v.w - mr);
    *(float4*)dst = o;
}

// LDS float offsets
#define O_ELT 0        // 64*29 = 1856   elT[t][pos]  (pitch 29)
#define O_ELN 1856     // 6240           elN[(kl-1)*32*SP + l*SP + s]
#define O_ERN 8096     // 6240           erN[k*32*SP + r*SP + s]
#define O_BPR 14336    // 28*32          betaPrev[s*32+a]
#define O_BMX 15232    // 28*28          bmaxAll[k*NMAX+pos]
#define O_MSP 16016    // 28
#define O_GT  16044    // 28
#define O_NUM 16072    // 27*260 = 7020  numer[s*260 + cL]
#define LDSF  23092
// red[g16][s][a] (16*28*32=14336) aliases O_ELT..O_ERN end (exactly 14336)

__global__ __launch_bounds__(512) void step_kernel(
    const float* __restrict__ unary, const float* __restrict__ mrule,
    float* __restrict__ bmax_g, float* __restrict__ beta_n,
    const float* __restrict__ E_TT, const float* __restrict__ E_TN,
    const float* __restrict__ E_NT, const float* __restrict__ E_NN,
    const float* __restrict__ pin, float* __restrict__ pout,
    const float* __restrict__ Min, float* __restrict__ Mout,
    int w, int n) {
    extern __shared__ float lds[];
    const int b = blockIdx.y, ch = blockIdx.x, tid = threadIdx.x;
    const int S = n - w, SP = S | 1;
    const int a = tid & 31, g16 = tid >> 5;   // g16: 0..15

    // ---- quadrant select + early E register loads (coalesced, once) ----
    int quad, base4;
    const float4* Eq;
    if (w == 1)       { quad = 0; base4 = ch * 64;        Eq = (const float4*)E_TT + (size_t)b * 32768; }
    else if (ch < 8)  { quad = 1; base4 = ch * 64;        Eq = (const float4*)E_TN + (size_t)b * 16384; }
    else if (ch < 16) { quad = 2; base4 = (ch - 8) * 64;  Eq = (const float4*)E_NT + (size_t)b * 16384; }
    else              { quad = 3; base4 = (ch - 16) * 64; Eq = (const float4*)E_NN + (size_t)b * 8192; }
    float4 e4[4];
    #pragma unroll
    for (int i = 0; i < 4; ++i)
        e4[i] = Eq[(size_t)(base4 + g16 * 4 + i) * 32 + a];

    // ---- P0: finalize prev width (w>=2) OR bmax0 (w==1); stage bmax rows ----
    if (w >= 2) {
        const int wp = w - 1, Sp = S + 1;
        const int CHp = (wp >= 3) ? 20 : 16;
        const float* pb = pin + (size_t)b * (PS * 32 * PCH);
        for (int e = tid; e < Sp * 32; e += 512) {
            const float4* p4 = (const float4*)(pb + e * PCH);
            float4 q0 = p4[0], q1 = p4[1], q2 = p4[2], q3 = p4[3];
            float t = ((q0.x + q0.y) + (q0.z + q0.w)) + ((q1.x + q1.y) + (q1.z + q1.w))
                    + ((q2.x + q2.y) + (q2.z + q2.w)) + ((q3.x + q3.y) + (q3.z + q3.w));
            if (CHp == 20) { float4 q4 = p4[4]; t += ((q4.x + q4.y) + (q4.z + q4.w)); }
            int s = e >> 5, aa = e & 31;
            float score = logf(t) + Min[b * PS + s] + mrule[b * 32 + aa];
            lds[O_BPR + e] = score;
            beta_n[(((size_t)b * n + wp) * n + s) * 32 + aa] = score;
        }
        for (int idx = tid; idx < (w - 1) * n; idx += 512) {
            int k = idx / n, pos = idx - k * n;
            lds[O_BMX + k * NMAX + pos] = bmax_g[((size_t)b * n + k) * n + pos];
        }
    } else {
        // bmax0 via wave reductions over unary rows
        for (int pos = tid >> 6; pos < n; pos += 8) {
            int t = tid & 63;
            float v = unary[((size_t)(b * n + pos)) * 64 + t];
            for (int off = 32; off > 0; off >>= 1) v = fmaxf(v, __shfl_xor(v, off, 64));
            if (t == 0) {
                lds[O_BMX + pos] = v;
                bmax_g[((size_t)b * n + 0) * n + pos] = v;
            }
        }
    }
    __syncthreads();

    // ---- P1: bmax row w-1 (w>=2) + elT ----
    if (w >= 2) {
        const int Sp = S + 1;
        for (int s0 = g16; s0 < Sp; s0 += 16) {
            float v = lds[O_BPR + s0 * 32 + a];
            for (int off = 16; off > 0; off >>= 1) v = fmaxf(v, __shfl_xor(v, off, 32));
            if (a == 0) {
                lds[O_BMX + (w - 1) * NMAX + s0] = v;
                bmax_g[((size_t)b * n + (w - 1)) * n + s0] = v;
            }
        }
    }
    for (int idx = tid; idx < n * 64; idx += 512) {
        int t = idx & 63, pos = idx >> 6;
        lds[O_ELT + t * 29 + pos] =
            expf(unary[((size_t)(b * n + pos)) * 64 + t] - lds[O_BMX + pos]);
    }
    __syncthreads();

    // ---- P2: Mspan + gT ----
    if (tid < S) {
        int s = tid;
        float M = -3.0e38f;
        for (int k = 0; k < w; ++k)
            M = fmaxf(M, lds[O_BMX + k * NMAX + s] +
                          lds[O_BMX + (w - 1 - k) * NMAX + s + k + 1]);
        lds[O_MSP + s] = M;
        lds[O_GT + s] = expf(lds[O_BMX + (w - 1) * NMAX + s] + lds[O_BMX + s + w] - M);
    }
    __syncthreads();

    // ---- P3: elN / erN tables (w>=2) ----
    if (w >= 2) {
        const int sym = tid & 31, s0 = tid >> 5;  // s0: 0..15
        for (int kl = 1; kl < w; ++kl) {
            const float* src = beta_n + (((size_t)b * n + kl) * n) * 32;
            for (int s = s0; s < S; s += 16) {
                float v = (kl == w - 1) ? lds[O_BPR + s * 32 + sym] : src[s * 32 + sym];
                lds[O_ELN + (kl - 1) * 32 * SP + sym * SP + s] =
                    expf(v - lds[O_BMX + kl * NMAX + s]);
            }
        }
        for (int k = 0; k < w - 1; ++k) {
            const int wr = w - 1 - k;
            const float* src = beta_n + (((size_t)b * n + wr) * n) * 32;
            for (int s = s0; s < S; s += 16) {
                float v = (k == 0) ? lds[O_BPR + (s + 1) * 32 + sym]
                                   : src[(s + k + 1) * 32 + sym];
                lds[O_ERN + k * 32 * SP + sym * SP + s] =
                    expf(v + lds[O_BMX + k * NMAX + s] - lds[O_MSP + s]);
            }
        }
        __syncthreads();
    }

    // ---- P4: numer build, all spans ----
    {
        const int cL = tid & 255, sh2 = tid >> 8;
        int l, r;
        if (quad == 0)      { int cc = ch * 256 + cL;        l = cc >> 6; r = cc & 63; }
        else if (quad == 1) { int cc = ch * 256 + cL;        l = cc >> 5; r = cc & 31; }
        else if (quad == 2) { int cc = (ch - 8) * 256 + cL;  l = cc >> 6; r = cc & 63; }
        else                { int cc = (ch - 16) * 256 + cL; l = cc >> 5; r = cc & 31; }
        for (int s = sh2; s < S; s += 2) {
            float v;
            if (quad == 0)
                v = lds[O_ELT + l * 29 + s] * lds[O_ELT + r * 29 + (s + 1)] * lds[O_GT + s];
            else if (quad == 1)
                v = lds[O_ELT + l * 29 + s] * lds[O_ERN + r * SP + s];
            else if (quad == 2)
                v = lds[O_ELN + (w - 2) * 32 * SP + l * SP + s] *
                    lds[O_ELT + r * 29 + (s + w)] * lds[O_GT + s];
            else {
                float acc = 0.f;
                for (int k = 1; k <= w - 2; ++k)
                    acc = fmaf(lds[O_ELN + (k - 1) * 32 * SP + l * SP + s],
                               lds[O_ERN + k * 32 * SP + r * SP + s], acc);
                v = acc;
            }
            lds[O_NUM + s * 260 + cL] = v;
        }
    }
    __syncthreads();

    // ---- P5: contraction (E in regs, numer broadcast from LDS) ----
    for (int s = 0; s < S; ++s) {
        float acc = 0.f;
        #pragma unroll
        for (int i = 0; i < 4; ++i) {
            const float4 nv = *(const float4*)&lds[O_NUM + s * 260 + (g16 * 4 + i) * 4];
            acc = dot4acc(nv, e4[i], acc);
        }
        lds[g16 * (NMAX * 32) + s * 32 + a] = acc;  // red aliases tables
    }
    __syncthreads();

    // ---- P6: reduce over g16, write chunk partials + M ----
    {
        float* pb = pout + (size_t)b * (PS * 32 * PCH);
        for (int e = tid; e < S * 32; e += 512) {
            float t = 0.f;
            for (int g2 = 0; g2 < 16; ++g2) t += lds[g2 * (NMAX * 32) + e];
            pb[e * PCH + ch] = t;
        }
        if (tid < S) Mout[b * PS + tid] = lds[O_MSP + tid];
    }
}

// ---- final: reduce last width's partials, add root, logsumexp ----
__global__ void final_kernel(const float* __restrict__ pin,
                             const float* __restrict__ Min,
                             const float* __restrict__ mrule,
                             const float* __restrict__ root,
                             float* __restrict__ out, int n) {
    int b = blockIdx.x, a = threadIdx.x; // block = 32
    int CHp = ((n - 1) >= 3) ? 20 : 16;
    const float4* p4 = (const float4*)(pin + (size_t)b * (PS * 32 * PCH) + a * PCH);
    float4 q0 = p4[0], q1 = p4[1], q2 = p4[2], q3 = p4[3];
    float t = ((q0.x + q0.y) + (q0.z + q0.w)) + ((q1.x + q1.y) + (q1.z + q1.w))
            + ((q2.x + q2.y) + (q2.z + q2.w)) + ((q3.x + q3.y) + (q3.z + q3.w));
    if (CHp == 20) { float4 q4 = p4[4]; t += ((q4.x + q4.y) + (q4.z + q4.w)); }
    float v = logf(t) + Min[b * PS] + mrule[b * 32 + a] + root[b * 32 + a];
    float m = v;
    for (int off = 16; off > 0; off >>= 1) m = fmaxf(m, __shfl_xor(m, off, 32));
    float e = expf(v - m);
    for (int off = 16; off > 0; off >>= 1) e += __shfl_xor(e, off, 32);
    if (a == 0) out[b] = m + logf(e);
}

extern "C" void kernel_launch(void* const* d_in, const int* in_sizes, int n_in,
                              void* d_out, int out_size, void* d_ws, size_t ws_size,
                              hipStream_t stream) {
    const float* unary = (const float*)d_in[0]; // B,n,64
    const float* rule  = (const float*)d_in[1]; // B,32,96,96
    const float* root  = (const float*)d_in[2]; // B,32
    float* out = (float*)d_out;

    const int B = in_sizes[2] / 32;
    int n = in_sizes[0] / (B * 64);

    float* ws = (float*)d_ws;
    float* mrule  = ws;                                 // B*32
    float* bmax_g = mrule + (size_t)B * 32;             // B*n*n
    float* beta_n = bmax_g + (size_t)B * n * n;         // B*n*n*32
    float* E_TT   = beta_n + (size_t)B * n * n * 32;    // B*1024*32*4
    float* E_TN   = E_TT + (size_t)B * 131072;          // B*512*32*4
    float* E_NT   = E_TN + (size_t)B * 65536;           // B*512*32*4
    float* E_NN   = E_NT + (size_t)B * 65536;           // B*256*32*4
    float* partA  = E_NN + (size_t)B * 32768;           // B*PS*32*PCH
    float* partB  = partA + (size_t)B * PS * 32 * PCH;
    float* MbufA  = partB + (size_t)B * PS * 32 * PCH;  // B*PS
    float* MbufB  = MbufA + (size_t)B * PS;

    mrule_kernel<<<dim3(32, B), 256, 0, stream>>>(rule, mrule);
    pack_kernel<<<dim3(288, B), 256, 0, stream>>>(rule, mrule, E_TT, E_TN, E_NT, E_NN);

    hipFuncSetAttribute((const void*)step_kernel,
                        hipFuncAttributeMaxDynamicSharedMemorySize, LDSF * 4);

    float* pbuf[2] = { partA, partB };
    float* mbuf[2] = { MbufA, MbufB };
    for (int w = 1; w < n; ++w) {
        int CH = (w >= 3) ? 20 : 16;
        step_kernel<<<dim3(CH, B), 512, LDSF * 4, stream>>>(
            unary, mrule, bmax_g, beta_n, E_TT, E_TN, E_NT, E_NN,
            pbuf[1 - (w & 1)], pbuf[w & 1], mbuf[1 - (w & 1)], mbuf[w & 1], w, n);
    }
    final_kernel<<<dim3(B), 32, 0, stream>>>(pbuf[(n - 1) & 1], mbuf[(n - 1) & 1],
                                             mrule, root, out, n);
}